// Round 7
// baseline (515.768 us; speedup 1.0000x reference)
//
#include <hip/hip_runtime.h>
#include <hip/hip_bf16.h>

// ModulatedConv2d b=16, ic=oc=512, k=3, h=w=64.
// R7: 256x256 tile, 8 waves. A (wmod) in LDS ring-4 (64KB, involution swizzle,
// linear-in-k staging => zero addr VALU). B (im2col from xT) DIRECT global->reg,
// prefetched one K-step ahead (ping-pong bfrA/bfrB). ONE barrier + one counted
// vmcnt per K-step => wave skew overlaps LDS pipe with MFMA pipe.

typedef __bf16 bf16x8 __attribute__((ext_vector_type(8)));
typedef float  f32x4  __attribute__((ext_vector_type(4)));

#define IC   512
#define OC   512
#define HW   4096
#define KTOT 4608

typedef __attribute__((address_space(3))) unsigned lds_u32;
typedef const __attribute__((address_space(1))) unsigned glb_u32;
#define GLL16(gsrc, ldst) \
    __builtin_amdgcn_global_load_lds((glb_u32*)(gsrc), (lds_u32*)(ldst), 16, 0, 0)
#define BAR()   asm volatile("s_barrier" ::: "memory")
#define SCHED0() __builtin_amdgcn_sched_barrier(0)

template<int N> __device__ __forceinline__ void vmw() {
    asm volatile("s_waitcnt vmcnt(%0)" :: "n"(N) : "memory");
}

// ---------------- kernel 1: style modulation s[b][i] ----------------
__global__ __launch_bounds__(256) void style_mod_kernel(
    const float* __restrict__ style, const float* __restrict__ mod_w,
    const float* __restrict__ mod_b, float* __restrict__ s_out)
{
    int pair = blockIdx.x * 4 + (threadIdx.x >> 6);
    int lane = threadIdx.x & 63;
    int b = pair >> 9;
    int i = pair & 511;
    const float4* sv = (const float4*)(style + b * 512);
    const float4* wv = (const float4*)(mod_w + i * 512);
    float4 a0 = sv[lane * 2], a1 = sv[lane * 2 + 1];
    float4 w0 = wv[lane * 2], w1 = wv[lane * 2 + 1];
    float sum = a0.x*w0.x + a0.y*w0.y + a0.z*w0.z + a0.w*w0.w
              + a1.x*w1.x + a1.y*w1.y + a1.z*w1.z + a1.w*w1.w;
    #pragma unroll
    for (int off = 32; off; off >>= 1) sum += __shfl_xor(sum, off);
    if (lane == 0) s_out[pair] = sum + mod_b[i];
}

// ------------- kernel 2: demod + bf16 wmod, layout [b][oc][tap*512+ic] -------------
__global__ __launch_bounds__(256) void wmod_kernel(
    const float* __restrict__ weight,   // [512][4608] (e = ic*9+tap)
    const float* __restrict__ s_in,
    __hip_bfloat16* __restrict__ wmod)  // [16*512][4608] (e' = tap*512+ic)
{
    int b  = blockIdx.x >> 9;
    int oc = blockIdx.x & 511;
    __shared__ float s_sh[512];
    __shared__ float red[256];
    int t = threadIdx.x;
    s_sh[t]       = s_in[b * 512 + t];
    s_sh[t + 256] = s_in[b * 512 + t + 256];
    __syncthreads();
    const float* wrow = weight + (size_t)oc * KTOT;
    float partial = 0.f;
    for (int e = t; e < KTOT; e += 256) {
        float v = wrow[e] * s_sh[e / 9];
        partial += v * v;
    }
    red[t] = partial;
    __syncthreads();
    #pragma unroll
    for (int off = 128; off; off >>= 1) {
        if (t < off) red[t] += red[t + off];
        __syncthreads();
    }
    float demod = rsqrtf(red[0] + 1e-8f);
    __hip_bfloat16* dst = wmod + (size_t)blockIdx.x * KTOT;
    for (int ep = t; ep < KTOT; ep += 256) {
        int tap = ep >> 9, ic = ep & 511;
        dst[ep] = __float2bfloat16(wrow[ic * 9 + tap] * s_sh[ic] * demod);
    }
}

// ------------- kernel 3a: zero pad row of xT -------------
__global__ void zero_row_kernel(__hip_bfloat16* xT) {
    ((unsigned*)(xT + ((size_t)blockIdx.x * 4097 + 4096) * 512))[threadIdx.x] = 0u;
}

// ------------- kernel 3b: x [b][ic][pix] f32 -> xT [b][pix][ic] bf16 -------------
__global__ __launch_bounds__(256) void xpose_kernel(
    const float* __restrict__ x, __hip_bfloat16* __restrict__ xT)
{
    __shared__ __align__(16) float tile[64][68];
    int b = blockIdx.z, ic0 = blockIdx.y * 64, p0 = blockIdx.x * 64;
    int t = threadIdx.x;
    const float* xb = x + ((size_t)b * 512 + ic0) * 4096 + p0;
    int rr = t >> 4, cc = (t & 15) * 4;
    #pragma unroll
    for (int i = 0; i < 4; ++i) {
        float4 v = *(const float4*)(xb + (size_t)(rr + i * 16) * 4096 + cc);
        *(float4*)&tile[rr + i * 16][cc] = v;
    }
    __syncthreads();
    int pr = t >> 2, io = (t & 3) * 16;
    __hip_bfloat16 obuf[16];
    #pragma unroll
    for (int j = 0; j < 16; ++j) obuf[j] = __float2bfloat16(tile[io + j][pr]);
    __hip_bfloat16* dst = xT + ((size_t)b * 4097 + p0 + pr) * 512 + ic0 + io;
    *(uint4*)dst       = *(uint4*)&obuf[0];
    *(uint4*)(dst + 8) = *(uint4*)&obuf[8];
}

// ------------- kernel 4: conv — A:LDS ring-4, B:reg-prefetch, 1 barrier/step -------------
__global__ __launch_bounds__(512, 2) void conv_kernel(
    const __hip_bfloat16* __restrict__ xT,    // [16][4097][512]
    const __hip_bfloat16* __restrict__ wmod,  // [16*512][4608]
    const float* __restrict__ bias,
    float* __restrict__ out)                  // [16][512][4096]
{
    __shared__ __align__(16) __hip_bfloat16 Ash[4][256 * 32];   // 64 KB ring

    const int t    = threadIdx.x;
    const int lane = t & 63;
    const int wid  = t >> 6;      // 0..7
    const int wm   = wid >> 2;    // 0..1 (M half, 128 rows)
    const int wn   = wid & 3;     // 0..3 (N quarter, 64 px)
    const int lr   = lane & 15;
    const int lq   = lane >> 4;

    // block decode: 512 blocks; per XCD 2 b's; oc-tile inner (B reuse in L2)
    int bid = blockIdx.x;
    int xcd = bid & 7, idx = bid >> 3;
    int oc1 = idx & 1;
    int nt  = (idx >> 1) & 15;
    int bb  = (idx >> 5) & 1;
    int b   = xcd * 2 + bb;
    int oc0 = oc1 * 256, n0 = nt * 256;

    const __hip_bfloat16* wb = wmod + (size_t)(b * 512 + oc0) * KTOT;
    const __hip_bfloat16* xb = xT + (size_t)b * 4097 * 512;

    // A staging: unit u (t, t+512): row u>>2, swizzled quad (u&3)^((u>>3)&3)
    const int qoff = (((t & 3) ^ ((t >> 3) & 3)) * 8);
    const __hip_bfloat16* pA0 = wb + (size_t)(t >> 2) * KTOT + qoff;   // rows 0..127
    const __hip_bfloat16* pA1 = pA0 + (size_t)128 * KTOT;              // rows 128..255

    __hip_bfloat16* const dA0[4] = {&Ash[0][t*8], &Ash[1][t*8], &Ash[2][t*8], &Ash[3][t*8]};
    __hip_bfloat16* const dA1[4] = {&Ash[0][(t+512)*8], &Ash[1][(t+512)*8],
                                    &Ash[2][(t+512)*8], &Ash[3][(t+512)*8]};

    // A fragment-read base (matching swizzle; proven conflict-free)
    const int swq = (lq ^ ((lr >> 1) & 3)) * 8;
    const int arb = (wm * 128 + lr) * 32 + swq;

    f32x4 acc[8][4] = {};
    bf16x8 bfrA[4], bfrB[4];
    const __hip_bfloat16 *pBF[4], *nBF[4];

    // per-tap B fragment pointers (pixel shifted by (dy,dx); OOB -> zero row 4096)
#define BPTR4(TAP, ARR) { \
    int dy = (TAP) / 3 - 1, dx = (TAP) % 3 - 1; \
    _Pragma("unroll") for (int ni = 0; ni < 4; ++ni) { \
        int p = n0 + wn * 64 + ni * 16 + lr; \
        int sy = (p >> 6) + dy, sx = (p & 63) + dx; \
        int pix = ((((unsigned)sy) < 64u) & (((unsigned)sx) < 64u)) ? ((sy << 6) + sx) : 4096; \
        ARR[ni] = xb + (size_t)pix * 512 + lq * 8; } }

    // one K-step: stage A(kk+3) [linear offset], load B(kk+1) -> BNXT,
    // counted vmcnt, ds_read A frags, 32 MFMA w/ BCUR, SCHED0+barrier.
    // BL_MODE: 1 = pBF + (CH+1)*32, 2 = nBF + 0 (tap boundary), 0 = none.
#define STEP(CH, BCUR, BNXT, DO_STAGE, BL_MODE, VN) { \
    const int sb_ = ((CH) + 3) & 3, cb_ = (CH) & 3; \
    if (DO_STAGE) { \
        GLL16(pA0 + ((CH) + 3) * 32, dA0[sb_]); \
        GLL16(pA1 + ((CH) + 3) * 32, dA1[sb_]); \
    } \
    if ((BL_MODE) == 1) { \
        _Pragma("unroll") for (int ni = 0; ni < 4; ++ni) \
            BNXT[ni] = *(const bf16x8*)(pBF[ni] + ((CH) + 1) * 32); \
    } else if ((BL_MODE) == 2) { \
        _Pragma("unroll") for (int ni = 0; ni < 4; ++ni) \
            BNXT[ni] = *(const bf16x8*)(nBF[ni]); \
    } \
    vmw<VN>(); \
    { \
        bf16x8 af0 = *(const bf16x8*)(&Ash[cb_][arb +   0]); \
        bf16x8 af1 = *(const bf16x8*)(&Ash[cb_][arb +  512]); \
        bf16x8 af2 = *(const bf16x8*)(&Ash[cb_][arb + 1024]); \
        bf16x8 af3 = *(const bf16x8*)(&Ash[cb_][arb + 1536]); \
        __builtin_amdgcn_s_setprio(1); \
        _Pragma("unroll") for (int ni = 0; ni < 4; ++ni) { \
            acc[0][ni] = __builtin_amdgcn_mfma_f32_16x16x32_bf16(af0, BCUR[ni], acc[0][ni], 0,0,0); \
            acc[1][ni] = __builtin_amdgcn_mfma_f32_16x16x32_bf16(af1, BCUR[ni], acc[1][ni], 0,0,0); \
            acc[2][ni] = __builtin_amdgcn_mfma_f32_16x16x32_bf16(af2, BCUR[ni], acc[2][ni], 0,0,0); \
            acc[3][ni] = __builtin_amdgcn_mfma_f32_16x16x32_bf16(af3, BCUR[ni], acc[3][ni], 0,0,0); \
        } \
        __builtin_amdgcn_s_setprio(0); \
    } \
    { \
        bf16x8 af4 = *(const bf16x8*)(&Ash[cb_][arb + 2048]); \
        bf16x8 af5 = *(const bf16x8*)(&Ash[cb_][arb + 2560]); \
        bf16x8 af6 = *(const bf16x8*)(&Ash[cb_][arb + 3072]); \
        bf16x8 af7 = *(const bf16x8*)(&Ash[cb_][arb + 3584]); \
        __builtin_amdgcn_s_setprio(1); \
        _Pragma("unroll") for (int ni = 0; ni < 4; ++ni) { \
            acc[4][ni] = __builtin_amdgcn_mfma_f32_16x16x32_bf16(af4, BCUR[ni], acc[4][ni], 0,0,0); \
            acc[5][ni] = __builtin_amdgcn_mfma_f32_16x16x32_bf16(af5, BCUR[ni], acc[5][ni], 0,0,0); \
            acc[6][ni] = __builtin_amdgcn_mfma_f32_16x16x32_bf16(af6, BCUR[ni], acc[6][ni], 0,0,0); \
            acc[7][ni] = __builtin_amdgcn_mfma_f32_16x16x32_bf16(af7, BCUR[ni], acc[7][ni], 0,0,0); \
        } \
        __builtin_amdgcn_s_setprio(0); \
    } \
    SCHED0(); \
    BAR(); }

    // ---- prologue: stage A(0..2), load B(0); A(0) retired before loop ----
    BPTR4(0, pBF);
    GLL16(pA0 +  0, dA0[0]); GLL16(pA1 +  0, dA1[0]);
    GLL16(pA0 + 32, dA0[1]); GLL16(pA1 + 32, dA1[1]);
    GLL16(pA0 + 64, dA0[2]); GLL16(pA1 + 64, dA1[2]);
    #pragma unroll
    for (int ni = 0; ni < 4; ++ni) bfrA[ni] = *(const bf16x8*)(pBF[ni]);
    vmw<8>();
    BAR();

    // ---- taps 0..7: full steps, vmcnt(18) ----
    for (int tap = 0; tap < 8; ++tap) {
        BPTR4(tap + 1, nBF);
        #pragma unroll
        for (int c2 = 0; c2 < 8; ++c2) {
            STEP(2*c2,     bfrA, bfrB, true, 1, 18);
            STEP(2*c2 + 1, bfrB, bfrA, true, ((2*c2 + 1) == 15 ? 2 : 1), 18);
        }
        pA0 += 512; pA1 += 512;
        #pragma unroll
        for (int ni = 0; ni < 4; ++ni) pBF[ni] = nBF[ni];
    }

    // ---- tap 8 (peeled tail): stop staging at ch>12, stop B loads at ch>14 ----
    STEP(0,  bfrA, bfrB, true, 1, 18);
    STEP(1,  bfrB, bfrA, true, 1, 18);
    STEP(2,  bfrA, bfrB, true, 1, 18);
    STEP(3,  bfrB, bfrA, true, 1, 18);
    STEP(4,  bfrA, bfrB, true, 1, 18);
    STEP(5,  bfrB, bfrA, true, 1, 18);
    STEP(6,  bfrA, bfrB, true, 1, 18);
    STEP(7,  bfrB, bfrA, true, 1, 18);
    STEP(8,  bfrA, bfrB, true, 1, 18);
    STEP(9,  bfrB, bfrA, true, 1, 18);
    STEP(10, bfrA, bfrB, true, 1, 18);
    STEP(11, bfrB, bfrA, true, 1, 18);
    STEP(12, bfrA, bfrB, true, 1, 18);
    STEP(13, bfrB, bfrA, false, 1, 16);
    STEP(14, bfrA, bfrB, false, 1, 14);
    STEP(15, bfrB, bfrA, false, 0, 8);
#undef STEP
#undef BPTR4

    // ---- epilogue ----
    #pragma unroll
    for (int mi = 0; mi < 8; ++mi) {
        int oc = oc0 + wm * 128 + mi * 16 + lq * 4;
        #pragma unroll
        for (int ni = 0; ni < 4; ++ni) {
            int n = n0 + wn * 64 + ni * 16 + lr;
            #pragma unroll
            for (int v = 0; v < 4; ++v) {
                float r = acc[mi][ni][v] + bias[oc + v];
                out[((size_t)(b * OC + oc + v)) * HW + n] = r;
            }
        }
    }
}

extern "C" void kernel_launch(void* const* d_in, const int* in_sizes, int n_in,
                              void* d_out, int out_size, void* d_ws, size_t ws_size,
                              hipStream_t stream) {
    const float* x      = (const float*)d_in[0];
    const float* style  = (const float*)d_in[1];
    const float* weight = (const float*)d_in[2];
    const float* bias   = (const float*)d_in[3];
    const float* mod_w  = (const float*)d_in[4];
    const float* mod_b  = (const float*)d_in[5];
    float* out = (float*)d_out;

    // ws: s [32KB] | wmod bf16 [75.5MB] | xT bf16 [67.2MB]
    float* s_ws = (float*)d_ws;
    __hip_bfloat16* wmod = (__hip_bfloat16*)((char*)d_ws + 32768);
    __hip_bfloat16* xT   = (__hip_bfloat16*)((char*)d_ws + 32768 + (size_t)16 * 512 * KTOT * 2);

    style_mod_kernel<<<2048, 256, 0, stream>>>(style, mod_w, mod_b, s_ws);
    wmod_kernel<<<16 * 512, 256, 0, stream>>>(weight, s_ws, wmod);
    zero_row_kernel<<<16, 256, 0, stream>>>(xT);
    dim3 tgrid(64, 8, 16);
    xpose_kernel<<<tgrid, 256, 0, stream>>>(x, xT);
    conv_kernel<<<512, 512, 0, stream>>>(xT, wmod, bias, out);
}

// Round 8
// 423.003 us; speedup vs baseline: 1.2193x; 1.2193x over previous
//
#include <hip/hip_runtime.h>
#include <hip/hip_bf16.h>

// ModulatedConv2d b=16, ic=oc=512, k=3, h=w=64.
// R8: 256(oc)x128(px) tile, BK=32, 4 waves, LDS ring-3 (72KB) => 2 blocks/CU.
// Two independent barrier domains per CU: block A's MFMA overlaps block B's
// LDS reads. Keeps R5/R6 proven parts: counted vmcnt(6), involution swizzle
// (0 conflicts), linear A stage offsets, per-tap hoisted B pointers, setprio.

typedef __bf16 bf16x8 __attribute__((ext_vector_type(8)));
typedef float  f32x4  __attribute__((ext_vector_type(4)));

#define IC   512
#define OC   512
#define HW   4096
#define KTOT 4608

typedef __attribute__((address_space(3))) unsigned lds_u32;
typedef const __attribute__((address_space(1))) unsigned glb_u32;
#define GLL16(gsrc, ldst) \
    __builtin_amdgcn_global_load_lds((glb_u32*)(gsrc), (lds_u32*)(ldst), 16, 0, 0)
#define BAR()   asm volatile("s_barrier" ::: "memory")

template<int N> __device__ __forceinline__ void vmw() {
    asm volatile("s_waitcnt vmcnt(%0)" :: "n"(N) : "memory");
}

// ---------------- kernel 1: style modulation s[b][i] ----------------
__global__ __launch_bounds__(256) void style_mod_kernel(
    const float* __restrict__ style, const float* __restrict__ mod_w,
    const float* __restrict__ mod_b, float* __restrict__ s_out)
{
    int pair = blockIdx.x * 4 + (threadIdx.x >> 6);
    int lane = threadIdx.x & 63;
    int b = pair >> 9;
    int i = pair & 511;
    const float4* sv = (const float4*)(style + b * 512);
    const float4* wv = (const float4*)(mod_w + i * 512);
    float4 a0 = sv[lane * 2], a1 = sv[lane * 2 + 1];
    float4 w0 = wv[lane * 2], w1 = wv[lane * 2 + 1];
    float sum = a0.x*w0.x + a0.y*w0.y + a0.z*w0.z + a0.w*w0.w
              + a1.x*w1.x + a1.y*w1.y + a1.z*w1.z + a1.w*w1.w;
    #pragma unroll
    for (int off = 32; off; off >>= 1) sum += __shfl_xor(sum, off);
    if (lane == 0) s_out[pair] = sum + mod_b[i];
}

// ------------- kernel 2: demod + bf16 wmod, layout [b][oc][tap*512+ic] -------------
// block order b-INNER (bid = oc*16 + b): 16 consecutive blocks share one
// weight row -> L2 reuse (weight re-read was ~150MB of HBM before).
__global__ __launch_bounds__(256) void wmod_kernel(
    const float* __restrict__ weight,   // [512][4608] (e = ic*9+tap)
    const float* __restrict__ s_in,
    __hip_bfloat16* __restrict__ wmod)  // [16*512][4608] (e' = tap*512+ic)
{
    int oc = blockIdx.x >> 4;
    int b  = blockIdx.x & 15;
    __shared__ float s_sh[512];
    __shared__ float red[256];
    int t = threadIdx.x;
    s_sh[t]       = s_in[b * 512 + t];
    s_sh[t + 256] = s_in[b * 512 + t + 256];
    __syncthreads();
    const float* wrow = weight + (size_t)oc * KTOT;
    float partial = 0.f;
    for (int e = t; e < KTOT; e += 256) {
        float v = wrow[e] * s_sh[e / 9];
        partial += v * v;
    }
    red[t] = partial;
    __syncthreads();
    #pragma unroll
    for (int off = 128; off; off >>= 1) {
        if (t < off) red[t] += red[t + off];
        __syncthreads();
    }
    float demod = rsqrtf(red[0] + 1e-8f);
    __hip_bfloat16* dst = wmod + ((size_t)b * 512 + oc) * KTOT;
    for (int ep = t; ep < KTOT; ep += 256) {
        int tap = ep >> 9, ic = ep & 511;
        dst[ep] = __float2bfloat16(wrow[ic * 9 + tap] * s_sh[ic] * demod);
    }
}

// ------------- kernel 3a: zero pad row of xT -------------
__global__ void zero_row_kernel(__hip_bfloat16* xT) {
    ((unsigned*)(xT + ((size_t)blockIdx.x * 4097 + 4096) * 512))[threadIdx.x] = 0u;
}

// ------------- kernel 3b: x [b][ic][pix] f32 -> xT [b][pix][ic] bf16 -------------
__global__ __launch_bounds__(256) void xpose_kernel(
    const float* __restrict__ x, __hip_bfloat16* __restrict__ xT)
{
    __shared__ __align__(16) float tile[64][68];
    int b = blockIdx.z, ic0 = blockIdx.y * 64, p0 = blockIdx.x * 64;
    int t = threadIdx.x;
    const float* xb = x + ((size_t)b * 512 + ic0) * 4096 + p0;
    int rr = t >> 4, cc = (t & 15) * 4;
    #pragma unroll
    for (int i = 0; i < 4; ++i) {
        float4 v = *(const float4*)(xb + (size_t)(rr + i * 16) * 4096 + cc);
        *(float4*)&tile[rr + i * 16][cc] = v;
    }
    __syncthreads();
    int pr = t >> 2, io = (t & 3) * 16;
    __hip_bfloat16 obuf[16];
    #pragma unroll
    for (int j = 0; j < 16; ++j) obuf[j] = __float2bfloat16(tile[io + j][pr]);
    __hip_bfloat16* dst = xT + ((size_t)b * 4097 + p0 + pr) * 512 + ic0 + io;
    *(uint4*)dst       = *(uint4*)&obuf[0];
    *(uint4*)(dst + 8) = *(uint4*)&obuf[8];
}

// ------------- kernel 4: conv, 256x128 ring-3, 2 blocks/CU -------------
__global__ __launch_bounds__(256, 2) void conv_kernel(
    const __hip_bfloat16* __restrict__ xT,    // [16][4097][512]
    const __hip_bfloat16* __restrict__ wmod,  // [16*512][4608]
    const float* __restrict__ bias,
    float* __restrict__ out)                  // [16][512][4096]
{
    // ring-3: A slot 256x32 (8192 elems, 16KB), B slot 128x32 (4096 elems, 8KB)
    __shared__ __align__(16) __hip_bfloat16 AshF[3 * 256 * 32];
    __shared__ __align__(16) __hip_bfloat16 BshF[3 * 128 * 32];

    const int t    = threadIdx.x;
    const int lane = t & 63;
    const int wid  = t >> 6;      // 0..3
    const int wm   = wid >> 1;    // 0..1 (M half: 128 oc rows)
    const int wn   = wid & 1;     // 0..1 (N half: 64 px)
    const int lr   = lane & 15;
    const int lq   = lane >> 4;

    // block decode: 1024 blocks; per XCD 2 b's; mt INNER (2 consecutive blocks
    // share the B panel and typically co-reside on one CU)
    int bid = blockIdx.x;
    int xcd = bid & 7, idx = bid >> 3;
    int mt  = idx & 1;
    int nt  = (idx >> 1) & 31;
    int bb  = idx >> 6;
    int b   = xcd * 2 + bb;
    int oc0 = mt * 256, n0 = nt * 128;

    const __hip_bfloat16* wb = wmod + (size_t)(b * 512 + oc0) * KTOT;
    const __hip_bfloat16* xb = xT + (size_t)b * 4097 * 512;

    // stage geometry: unit u -> row u>>2, phys quad u&3; involution swizzle:
    // stored quad = (u&3) ^ ((u>>3)&3) (== quad ^ ((row>>1)&3)); one qoff
    // serves all of a thread's units (rows differ by multiples of 64).
    const int qoff = (((t & 3) ^ ((t >> 3) & 3)) * 8);
    const int srow = t >> 2;                 // 0..63
    const int p0g  = n0 + srow;
    const int y0p  = p0g >> 6, x0p = p0g & 63;

    // A: 4 units/thread -> rows srow + {0,64,128,192}
    const __hip_bfloat16* pA0 = wb + (size_t)srow * KTOT + qoff;
    const __hip_bfloat16* pA1 = pA0 + (size_t)64  * KTOT;
    const __hip_bfloat16* pA2 = pA0 + (size_t)128 * KTOT;
    const __hip_bfloat16* pA3 = pA0 + (size_t)192 * KTOT;

    // rotating ring-slot element offsets (slot of tile k = k%3 = (tap+ch)%3)
    int soA0 = 0, soA1 = 8192, soA2 = 16384;
    int soB0 = 0, soB1 = 4096, soB2 = 8192;
#define SOA(i) (((i) % 3) == 0 ? soA0 : (((i) % 3) == 1 ? soA1 : soA2))
#define SOB(i) (((i) % 3) == 0 ? soB0 : (((i) % 3) == 1 ? soB1 : soB2))

    // fragment-read bases with matching swizzle (verified 0 conflicts)
    const int swq = (lq ^ ((lr >> 1) & 3)) * 8;
    const int arb = (wm * 128 + lr) * 32 + swq;
    const int brb = (wn * 64  + lr) * 32 + swq;

    f32x4 acc[8][4] = {};

    // per-tap B pixel pointers (rows srow, srow+64; OOB -> zero row 4096)
    const __hip_bfloat16 *pB0, *pB1, *nB0, *nB1;
    auto bptrs = [&](int tap, const __hip_bfloat16*& P0, const __hip_bfloat16*& P1) {
        int dy = tap / 3 - 1, dx = tap % 3 - 1;
        int sy = y0p + dy, sx = x0p + dx;
        int pix0 = ((((unsigned)sy)  < 64u) & (((unsigned)sx) < 64u)) ? ((sy  << 6) + sx) : 4096;
        int sy1 = sy + 1;   // second unit is +64 pixels = +1 image row
        int pix1 = ((((unsigned)sy1) < 64u) & (((unsigned)sx) < 64u)) ? ((sy1 << 6) + sx) : 4096;
        P0 = xb + (size_t)pix0 * 512 + qoff;
        P1 = xb + (size_t)pix1 * 512 + qoff;
    };

#define STAGE_A(SO, OFF) { \
    GLL16(pA0 + (OFF), &AshF[(SO) + t * 8]); \
    GLL16(pA1 + (OFF), &AshF[(SO) + (t + 256) * 8]); \
    GLL16(pA2 + (OFF), &AshF[(SO) + (t + 512) * 8]); \
    GLL16(pA3 + (OFF), &AshF[(SO) + (t + 768) * 8]); }
#define STAGE_B(SO, Q0, Q1, OFF) { \
    GLL16((Q0) + (OFF), &BshF[(SO) + t * 8]); \
    GLL16((Q1) + (OFF), &BshF[(SO) + (t + 256) * 8]); }

// one K-step: read frags(ch), stage tile ch+2 (A linear; B from pB/nB),
// 32 MFMA setprio-wrapped, counted vmcnt, barrier.
#define STEP(CH, DO_STAGE, B_NEXT, VN) { \
    bf16x8 af[8], bfr[4]; \
    _Pragma("unroll") for (int mi = 0; mi < 8; ++mi) \
        af[mi] = *(const bf16x8*)(&AshF[SOA(CH) + arb + mi * 512]); \
    _Pragma("unroll") for (int ni = 0; ni < 4; ++ni) \
        bfr[ni] = *(const bf16x8*)(&BshF[SOB(CH) + brb + ni * 512]); \
    if (DO_STAGE) { \
        STAGE_A(SOA((CH) + 2), ((CH) + 2) * 32); \
        if (B_NEXT) { STAGE_B(SOB((CH) + 2), nB0, nB1, ((CH) - 14) * 32); } \
        else        { STAGE_B(SOB((CH) + 2), pB0, pB1, ((CH) + 2) * 32); } \
    } \
    __builtin_amdgcn_s_setprio(1); \
    _Pragma("unroll") for (int mi = 0; mi < 8; ++mi) \
        _Pragma("unroll") for (int ni = 0; ni < 4; ++ni) \
            acc[mi][ni] = __builtin_amdgcn_mfma_f32_16x16x32_bf16( \
                af[mi], bfr[ni], acc[mi][ni], 0, 0, 0); \
    __builtin_amdgcn_s_setprio(0); \
    vmw<VN>(); \
    BAR(); }

    // ---- prologue: stage tiles 0 (slot0) and 1 (slot1), both tap 0 ----
    bptrs(0, pB0, pB1);
    STAGE_A(0, 0);      STAGE_B(0, pB0, pB1, 0);
    STAGE_A(8192, 32);  STAGE_B(4096, pB0, pB1, 32);
    vmw<6>();           // tile 0 resident (tile 1's 6 may fly)
    BAR();

    // ---- taps 0..7 ----
    for (int tap = 0; tap < 8; ++tap) {
        bptrs(tap + 1, nB0, nB1);
        #pragma unroll
        for (int ch = 0; ch < 16; ++ch) {
            STEP(ch, true, (ch >= 14), 6);
        }
        // rotate ring (16 steps ≡ 1 mod 3)
        int ta = soA0; soA0 = soA1; soA1 = soA2; soA2 = ta;
        int tb = soB0; soB0 = soB1; soB1 = soB2; soB2 = tb;
        pA0 += 512; pA1 += 512; pA2 += 512; pA3 += 512;
        pB0 = nB0; pB1 = nB1;
    }

    // ---- tap 8 (peeled): stage while k+2 <= 143 (ch <= 13) ----
    #pragma unroll
    for (int ch = 0; ch < 13; ++ch) {
        STEP(ch, true, false, 6);
    }
    STEP(13, true,  false, 6);   // stages tile 143
    STEP(14, false, false, 0);   // drain: tile 143 resident
    {   // ch = 15: last compute, no stage/sync
        bf16x8 af[8], bfr[4];
        #pragma unroll
        for (int mi = 0; mi < 8; ++mi)
            af[mi] = *(const bf16x8*)(&AshF[SOA(15) + arb + mi * 512]);
        #pragma unroll
        for (int ni = 0; ni < 4; ++ni)
            bfr[ni] = *(const bf16x8*)(&BshF[SOB(15) + brb + ni * 512]);
        #pragma unroll
        for (int mi = 0; mi < 8; ++mi)
            #pragma unroll
            for (int ni = 0; ni < 4; ++ni)
                acc[mi][ni] = __builtin_amdgcn_mfma_f32_16x16x32_bf16(
                    af[mi], bfr[ni], acc[mi][ni], 0, 0, 0);
    }
#undef STEP
#undef STAGE_A
#undef STAGE_B
#undef SOA
#undef SOB

    // ---- epilogue ----
    #pragma unroll
    for (int mi = 0; mi < 8; ++mi) {
        int oc = oc0 + wm * 128 + mi * 16 + lq * 4;
        #pragma unroll
        for (int ni = 0; ni < 4; ++ni) {
            int n = n0 + wn * 64 + ni * 16 + lr;
            #pragma unroll
            for (int v = 0; v < 4; ++v) {
                float r = acc[mi][ni][v] + bias[oc + v];
                out[((size_t)(b * OC + oc + v)) * HW + n] = r;
            }
        }
    }
}

extern "C" void kernel_launch(void* const* d_in, const int* in_sizes, int n_in,
                              void* d_out, int out_size, void* d_ws, size_t ws_size,
                              hipStream_t stream) {
    const float* x      = (const float*)d_in[0];
    const float* style  = (const float*)d_in[1];
    const float* weight = (const float*)d_in[2];
    const float* bias   = (const float*)d_in[3];
    const float* mod_w  = (const float*)d_in[4];
    const float* mod_b  = (const float*)d_in[5];
    float* out = (float*)d_out;

    // ws: s [32KB] | wmod bf16 [75.5MB] | xT bf16 [67.2MB]
    float* s_ws = (float*)d_ws;
    __hip_bfloat16* wmod = (__hip_bfloat16*)((char*)d_ws + 32768);
    __hip_bfloat16* xT   = (__hip_bfloat16*)((char*)d_ws + 32768 + (size_t)16 * 512 * KTOT * 2);

    style_mod_kernel<<<2048, 256, 0, stream>>>(style, mod_w, mod_b, s_ws);
    wmod_kernel<<<16 * 512, 256, 0, stream>>>(weight, s_ws, wmod);
    zero_row_kernel<<<16, 256, 0, stream>>>(xT);
    dim3 tgrid(64, 8, 16);
    xpose_kernel<<<tgrid, 256, 0, stream>>>(x, xT);
    conv_kernel<<<1024, 256, 0, stream>>>(xT, wmod, bias, out);
}

// Round 9
// 421.894 us; speedup vs baseline: 1.2225x; 1.0026x over previous
//
#include <hip/hip_runtime.h>
#include <hip/hip_bf16.h>

// ModulatedConv2d b=16, ic=oc=512, k=3, h=w=64.
// R8: 256(oc)x128(px) tile, BK=32, 4 waves, LDS ring-3 (72KB) => 2 blocks/CU.
// Two independent barrier domains per CU: block A's MFMA overlaps block B's
// LDS reads. Keeps R5/R6 proven parts: counted vmcnt(6), involution swizzle
// (0 conflicts), linear A stage offsets, per-tap hoisted B pointers, setprio.

typedef __bf16 bf16x8 __attribute__((ext_vector_type(8)));
typedef float  f32x4  __attribute__((ext_vector_type(4)));

#define IC   512
#define OC   512
#define HW   4096
#define KTOT 4608

typedef __attribute__((address_space(3))) unsigned lds_u32;
typedef const __attribute__((address_space(1))) unsigned glb_u32;
#define GLL16(gsrc, ldst) \
    __builtin_amdgcn_global_load_lds((glb_u32*)(gsrc), (lds_u32*)(ldst), 16, 0, 0)
#define BAR()   asm volatile("s_barrier" ::: "memory")

template<int N> __device__ __forceinline__ void vmw() {
    asm volatile("s_waitcnt vmcnt(%0)" :: "n"(N) : "memory");
}

// ---------------- kernel 1: style modulation s[b][i] ----------------
__global__ __launch_bounds__(256) void style_mod_kernel(
    const float* __restrict__ style, const float* __restrict__ mod_w,
    const float* __restrict__ mod_b, float* __restrict__ s_out)
{
    int pair = blockIdx.x * 4 + (threadIdx.x >> 6);
    int lane = threadIdx.x & 63;
    int b = pair >> 9;
    int i = pair & 511;
    const float4* sv = (const float4*)(style + b * 512);
    const float4* wv = (const float4*)(mod_w + i * 512);
    float4 a0 = sv[lane * 2], a1 = sv[lane * 2 + 1];
    float4 w0 = wv[lane * 2], w1 = wv[lane * 2 + 1];
    float sum = a0.x*w0.x + a0.y*w0.y + a0.z*w0.z + a0.w*w0.w
              + a1.x*w1.x + a1.y*w1.y + a1.z*w1.z + a1.w*w1.w;
    #pragma unroll
    for (int off = 32; off; off >>= 1) sum += __shfl_xor(sum, off);
    if (lane == 0) s_out[pair] = sum + mod_b[i];
}

// ------------- kernel 2: demod + bf16 wmod, layout [b][oc][tap*512+ic] -------------
// block order b-INNER (bid = oc*16 + b): 16 consecutive blocks share one
// weight row -> L2 reuse (weight re-read was ~150MB of HBM before).
__global__ __launch_bounds__(256) void wmod_kernel(
    const float* __restrict__ weight,   // [512][4608] (e = ic*9+tap)
    const float* __restrict__ s_in,
    __hip_bfloat16* __restrict__ wmod)  // [16*512][4608] (e' = tap*512+ic)
{
    int oc = blockIdx.x >> 4;
    int b  = blockIdx.x & 15;
    __shared__ float s_sh[512];
    __shared__ float red[256];
    int t = threadIdx.x;
    s_sh[t]       = s_in[b * 512 + t];
    s_sh[t + 256] = s_in[b * 512 + t + 256];
    __syncthreads();
    const float* wrow = weight + (size_t)oc * KTOT;
    float partial = 0.f;
    for (int e = t; e < KTOT; e += 256) {
        float v = wrow[e] * s_sh[e / 9];
        partial += v * v;
    }
    red[t] = partial;
    __syncthreads();
    #pragma unroll
    for (int off = 128; off; off >>= 1) {
        if (t < off) red[t] += red[t + off];
        __syncthreads();
    }
    float demod = rsqrtf(red[0] + 1e-8f);
    __hip_bfloat16* dst = wmod + ((size_t)b * 512 + oc) * KTOT;
    for (int ep = t; ep < KTOT; ep += 256) {
        int tap = ep >> 9, ic = ep & 511;
        dst[ep] = __float2bfloat16(wrow[ic * 9 + tap] * s_sh[ic] * demod);
    }
}

// ------------- kernel 3a: zero pad row of xT -------------
__global__ void zero_row_kernel(__hip_bfloat16* xT) {
    ((unsigned*)(xT + ((size_t)blockIdx.x * 4097 + 4096) * 512))[threadIdx.x] = 0u;
}

// ------------- kernel 3b: x [b][ic][pix] f32 -> xT [b][pix][ic] bf16 -------------
__global__ __launch_bounds__(256) void xpose_kernel(
    const float* __restrict__ x, __hip_bfloat16* __restrict__ xT)
{
    __shared__ __align__(16) float tile[64][68];
    int b = blockIdx.z, ic0 = blockIdx.y * 64, p0 = blockIdx.x * 64;
    int t = threadIdx.x;
    const float* xb = x + ((size_t)b * 512 + ic0) * 4096 + p0;
    int rr = t >> 4, cc = (t & 15) * 4;
    #pragma unroll
    for (int i = 0; i < 4; ++i) {
        float4 v = *(const float4*)(xb + (size_t)(rr + i * 16) * 4096 + cc);
        *(float4*)&tile[rr + i * 16][cc] = v;
    }
    __syncthreads();
    int pr = t >> 2, io = (t & 3) * 16;
    __hip_bfloat16 obuf[16];
    #pragma unroll
    for (int j = 0; j < 16; ++j) obuf[j] = __float2bfloat16(tile[io + j][pr]);
    __hip_bfloat16* dst = xT + ((size_t)b * 4097 + p0 + pr) * 512 + ic0 + io;
    *(uint4*)dst       = *(uint4*)&obuf[0];
    *(uint4*)(dst + 8) = *(uint4*)&obuf[8];
}

// ------------- kernel 4: conv, 256x128 ring-3, 2 blocks/CU -------------
__global__ __launch_bounds__(256, 2) void conv_kernel(
    const __hip_bfloat16* __restrict__ xT,    // [16][4097][512]
    const __hip_bfloat16* __restrict__ wmod,  // [16*512][4608]
    const float* __restrict__ bias,
    float* __restrict__ out)                  // [16][512][4096]
{
    // ring-3: A slot 256x32 (8192 elems, 16KB), B slot 128x32 (4096 elems, 8KB)
    __shared__ __align__(16) __hip_bfloat16 AshF[3 * 256 * 32];
    __shared__ __align__(16) __hip_bfloat16 BshF[3 * 128 * 32];

    const int t    = threadIdx.x;
    const int lane = t & 63;
    const int wid  = t >> 6;      // 0..3
    const int wm   = wid >> 1;    // 0..1 (M half: 128 oc rows)
    const int wn   = wid & 1;     // 0..1 (N half: 64 px)
    const int lr   = lane & 15;
    const int lq   = lane >> 4;

    // block decode: 1024 blocks; per XCD 2 b's; mt INNER (2 consecutive blocks
    // share the B panel and typically co-reside on one CU)
    int bid = blockIdx.x;
    int xcd = bid & 7, idx = bid >> 3;
    int mt  = idx & 1;
    int nt  = (idx >> 1) & 31;
    int bb  = idx >> 6;
    int b   = xcd * 2 + bb;
    int oc0 = mt * 256, n0 = nt * 128;

    const __hip_bfloat16* wb = wmod + (size_t)(b * 512 + oc0) * KTOT;
    const __hip_bfloat16* xb = xT + (size_t)b * 4097 * 512;

    // stage geometry: unit u -> row u>>2, phys quad u&3; involution swizzle:
    // stored quad = (u&3) ^ ((u>>3)&3) (== quad ^ ((row>>1)&3)); one qoff
    // serves all of a thread's units (rows differ by multiples of 64).
    const int qoff = (((t & 3) ^ ((t >> 3) & 3)) * 8);
    const int srow = t >> 2;                 // 0..63
    const int p0g  = n0 + srow;
    const int y0p  = p0g >> 6, x0p = p0g & 63;

    // A: 4 units/thread -> rows srow + {0,64,128,192}
    const __hip_bfloat16* pA0 = wb + (size_t)srow * KTOT + qoff;
    const __hip_bfloat16* pA1 = pA0 + (size_t)64  * KTOT;
    const __hip_bfloat16* pA2 = pA0 + (size_t)128 * KTOT;
    const __hip_bfloat16* pA3 = pA0 + (size_t)192 * KTOT;

    // rotating ring-slot element offsets (slot of tile k = k%3 = (tap+ch)%3)
    int soA0 = 0, soA1 = 8192, soA2 = 16384;
    int soB0 = 0, soB1 = 4096, soB2 = 8192;
#define SOA(i) (((i) % 3) == 0 ? soA0 : (((i) % 3) == 1 ? soA1 : soA2))
#define SOB(i) (((i) % 3) == 0 ? soB0 : (((i) % 3) == 1 ? soB1 : soB2))

    // fragment-read bases with matching swizzle (verified 0 conflicts)
    const int swq = (lq ^ ((lr >> 1) & 3)) * 8;
    const int arb = (wm * 128 + lr) * 32 + swq;
    const int brb = (wn * 64  + lr) * 32 + swq;

    f32x4 acc[8][4] = {};

    // per-tap B pixel pointers (rows srow, srow+64; OOB -> zero row 4096)
    const __hip_bfloat16 *pB0, *pB1, *nB0, *nB1;
    auto bptrs = [&](int tap, const __hip_bfloat16*& P0, const __hip_bfloat16*& P1) {
        int dy = tap / 3 - 1, dx = tap % 3 - 1;
        int sy = y0p + dy, sx = x0p + dx;
        int pix0 = ((((unsigned)sy)  < 64u) & (((unsigned)sx) < 64u)) ? ((sy  << 6) + sx) : 4096;
        int sy1 = sy + 1;   // second unit is +64 pixels = +1 image row
        int pix1 = ((((unsigned)sy1) < 64u) & (((unsigned)sx) < 64u)) ? ((sy1 << 6) + sx) : 4096;
        P0 = xb + (size_t)pix0 * 512 + qoff;
        P1 = xb + (size_t)pix1 * 512 + qoff;
    };

#define STAGE_A(SO, OFF) { \
    GLL16(pA0 + (OFF), &AshF[(SO) + t * 8]); \
    GLL16(pA1 + (OFF), &AshF[(SO) + (t + 256) * 8]); \
    GLL16(pA2 + (OFF), &AshF[(SO) + (t + 512) * 8]); \
    GLL16(pA3 + (OFF), &AshF[(SO) + (t + 768) * 8]); }
#define STAGE_B(SO, Q0, Q1, OFF) { \
    GLL16((Q0) + (OFF), &BshF[(SO) + t * 8]); \
    GLL16((Q1) + (OFF), &BshF[(SO) + (t + 256) * 8]); }

// one K-step: read frags(ch), stage tile ch+2 (A linear; B from pB/nB),
// 32 MFMA setprio-wrapped, counted vmcnt, barrier.
#define STEP(CH, DO_STAGE, B_NEXT, VN) { \
    bf16x8 af[8], bfr[4]; \
    _Pragma("unroll") for (int mi = 0; mi < 8; ++mi) \
        af[mi] = *(const bf16x8*)(&AshF[SOA(CH) + arb + mi * 512]); \
    _Pragma("unroll") for (int ni = 0; ni < 4; ++ni) \
        bfr[ni] = *(const bf16x8*)(&BshF[SOB(CH) + brb + ni * 512]); \
    if (DO_STAGE) { \
        STAGE_A(SOA((CH) + 2), ((CH) + 2) * 32); \
        if (B_NEXT) { STAGE_B(SOB((CH) + 2), nB0, nB1, ((CH) - 14) * 32); } \
        else        { STAGE_B(SOB((CH) + 2), pB0, pB1, ((CH) + 2) * 32); } \
    } \
    __builtin_amdgcn_s_setprio(1); \
    _Pragma("unroll") for (int mi = 0; mi < 8; ++mi) \
        _Pragma("unroll") for (int ni = 0; ni < 4; ++ni) \
            acc[mi][ni] = __builtin_amdgcn_mfma_f32_16x16x32_bf16( \
                af[mi], bfr[ni], acc[mi][ni], 0, 0, 0); \
    __builtin_amdgcn_s_setprio(0); \
    vmw<VN>(); \
    BAR(); }

    // ---- prologue: stage tiles 0 (slot0) and 1 (slot1), both tap 0 ----
    bptrs(0, pB0, pB1);
    STAGE_A(0, 0);      STAGE_B(0, pB0, pB1, 0);
    STAGE_A(8192, 32);  STAGE_B(4096, pB0, pB1, 32);
    vmw<6>();           // tile 0 resident (tile 1's 6 may fly)
    BAR();

    // ---- taps 0..7 ----
    for (int tap = 0; tap < 8; ++tap) {
        bptrs(tap + 1, nB0, nB1);
        #pragma unroll
        for (int ch = 0; ch < 16; ++ch) {
            STEP(ch, true, (ch >= 14), 6);
        }
        // rotate ring (16 steps ≡ 1 mod 3)
        int ta = soA0; soA0 = soA1; soA1 = soA2; soA2 = ta;
        int tb = soB0; soB0 = soB1; soB1 = soB2; soB2 = tb;
        pA0 += 512; pA1 += 512; pA2 += 512; pA3 += 512;
        pB0 = nB0; pB1 = nB1;
    }

    // ---- tap 8 (peeled): stage while k+2 <= 143 (ch <= 13) ----
    #pragma unroll
    for (int ch = 0; ch < 13; ++ch) {
        STEP(ch, true, false, 6);
    }
    STEP(13, true,  false, 6);   // stages tile 143
    STEP(14, false, false, 0);   // drain: tile 143 resident
    {   // ch = 15: last compute, no stage/sync
        bf16x8 af[8], bfr[4];
        #pragma unroll
        for (int mi = 0; mi < 8; ++mi)
            af[mi] = *(const bf16x8*)(&AshF[SOA(15) + arb + mi * 512]);
        #pragma unroll
        for (int ni = 0; ni < 4; ++ni)
            bfr[ni] = *(const bf16x8*)(&BshF[SOB(15) + brb + ni * 512]);
        #pragma unroll
        for (int mi = 0; mi < 8; ++mi)
            #pragma unroll
            for (int ni = 0; ni < 4; ++ni)
                acc[mi][ni] = __builtin_amdgcn_mfma_f32_16x16x32_bf16(
                    af[mi], bfr[ni], acc[mi][ni], 0, 0, 0);
    }
#undef STEP
#undef STAGE_A
#undef STAGE_B
#undef SOA
#undef SOB

    // ---- epilogue ----
    #pragma unroll
    for (int mi = 0; mi < 8; ++mi) {
        int oc = oc0 + wm * 128 + mi * 16 + lq * 4;
        #pragma unroll
        for (int ni = 0; ni < 4; ++ni) {
            int n = n0 + wn * 64 + ni * 16 + lr;
            #pragma unroll
            for (int v = 0; v < 4; ++v) {
                float r = acc[mi][ni][v] + bias[oc + v];
                out[((size_t)(b * OC + oc + v)) * HW + n] = r;
            }
        }
    }
}

extern "C" void kernel_launch(void* const* d_in, const int* in_sizes, int n_in,
                              void* d_out, int out_size, void* d_ws, size_t ws_size,
                              hipStream_t stream) {
    const float* x      = (const float*)d_in[0];
    const float* style  = (const float*)d_in[1];
    const float* weight = (const float*)d_in[2];
    const float* bias   = (const float*)d_in[3];
    const float* mod_w  = (const float*)d_in[4];
    const float* mod_b  = (const float*)d_in[5];
    float* out = (float*)d_out;

    // ws: s [32KB] | wmod bf16 [75.5MB] | xT bf16 [67.2MB]
    float* s_ws = (float*)d_ws;
    __hip_bfloat16* wmod = (__hip_bfloat16*)((char*)d_ws + 32768);
    __hip_bfloat16* xT   = (__hip_bfloat16*)((char*)d_ws + 32768 + (size_t)16 * 512 * KTOT * 2);

    style_mod_kernel<<<2048, 256, 0, stream>>>(style, mod_w, mod_b, s_ws);
    wmod_kernel<<<16 * 512, 256, 0, stream>>>(weight, s_ws, wmod);
    zero_row_kernel<<<16, 256, 0, stream>>>(xT);
    dim3 tgrid(64, 8, 16);
    xpose_kernel<<<tgrid, 256, 0, stream>>>(x, xT);
    conv_kernel<<<1024, 256, 0, stream>>>(xT, wmod, bias, out);
}